// Round 2
// baseline (368.847 us; speedup 1.0000x reference)
//
#include <hip/hip_runtime.h>
#include <hip/hip_bf16.h>

// SelfAttentionHead: B=4, S=4096, D=256, fp32 in/out.
// out = qp + softmax(tril_mul(qp kp^T / 16)) @ vp, masked entries enter softmax as 0.
// Split-K flash attention: grid (b, qtile64, khalf); combine kernel merges halves and
// applies the masked-zero correction: Z += (S-1-q)*e^{-M}, num += e^{-M}*SuffV[q].

typedef __bf16 bf16x8 __attribute__((ext_vector_type(8)));
typedef float f32x4 __attribute__((ext_vector_type(4)));

__device__ __forceinline__ unsigned short f2bf_u(float f) {
  unsigned u = __float_as_uint(f);
  u += 0x7fffu + ((u >> 16) & 1u);
  return (unsigned short)(u >> 16);
}

// ---------------- WT[j][k] = bf16(W[k][j]) ----------------
__global__ __launch_bounds__(256) void wt_kernel(
    const float* __restrict__ Wq, const float* __restrict__ Wk, const float* __restrict__ Wv,
    unsigned short* __restrict__ WTq, unsigned short* __restrict__ WTk, unsigned short* __restrict__ WTv) {
  int j = blockIdx.x & 255;
  int wsel = blockIdx.x >> 8;
  const float* W = wsel == 0 ? Wq : (wsel == 1 ? Wk : Wv);
  unsigned short* WT = wsel == 0 ? WTq : (wsel == 1 ? WTk : WTv);
  int k = threadIdx.x;
  WT[j * 256 + k] = f2bf_u(W[k * 256 + j]);
}

// ---------------- Projection GEMM ----------------
__global__ __launch_bounds__(256) void proj_kernel(
    const float* __restrict__ X, const unsigned short* __restrict__ WT,
    const float* __restrict__ bias, float* __restrict__ outf,
    unsigned short* __restrict__ outb, int mode) {
  int rt = blockIdx.x;
  int tid = threadIdx.x;
  int w = tid >> 6, l = tid & 63, g = l >> 4, lm = l & 15;
  int arow = rt * 64 + w * 16 + lm;

  f32x4 acc[16];
#pragma unroll
  for (int i = 0; i < 16; i++) acc[i] = (f32x4){0.f, 0.f, 0.f, 0.f};

#pragma unroll
  for (int kb = 0; kb < 256; kb += 32) {
    const float* ap = X + arow * 256 + kb + 8 * g;
    float4 a0 = *(const float4*)ap;
    float4 a1 = *(const float4*)(ap + 4);
    bf16x8 af;
    af[0] = (__bf16)a0.x; af[1] = (__bf16)a0.y; af[2] = (__bf16)a0.z; af[3] = (__bf16)a0.w;
    af[4] = (__bf16)a1.x; af[5] = (__bf16)a1.y; af[6] = (__bf16)a1.z; af[7] = (__bf16)a1.w;
#pragma unroll
    for (int nt = 0; nt < 16; nt++) {
      bf16x8 bf = *(const bf16x8*)(WT + (nt * 16 + lm) * 256 + kb + 8 * g);
      acc[nt] = __builtin_amdgcn_mfma_f32_16x16x32_bf16(af, bf, acc[nt], 0, 0, 0);
    }
  }

#pragma unroll
  for (int nt = 0; nt < 16; nt++) {
    int col = nt * 16 + lm;
    float bb = bias[col];
#pragma unroll
    for (int r = 0; r < 4; r++) {
      int orow = rt * 64 + w * 16 + 4 * g + r;
      float v = acc[nt][r] + bb;
      int idx = orow * 256 + col;
      if (mode == 0) {
        outf[idx] = v;
        outb[idx] = f2bf_u(v * 0.0625f);
      } else if (mode == 1) {
        outb[idx] = f2bf_u(v);
      } else {
        outf[idx] = v;
        int b = orow >> 12, s = orow & 4095;
        outb[(b * 256 + col) * 4096 + s] = f2bf_u(v);
      }
    }
  }
}

// ---------------- Suffix-sum of vp (exclusive), 64-row chunks ----------------
__global__ __launch_bounds__(256) void scan1(const float* __restrict__ vpf, float* __restrict__ ctot) {
  int c = blockIdx.x, b = blockIdx.y, d = threadIdx.x;
  const float* base = vpf + (b * 4096 + c * 64) * 256 + d;
  float acc = 0.f;
#pragma unroll 4
  for (int r = 0; r < 64; r++) acc += base[r * 256];
  ctot[(b * 64 + c) * 256 + d] = acc;
}

__global__ __launch_bounds__(256) void scan2(const float* __restrict__ vpf, const float* __restrict__ ctot,
                                             float* __restrict__ suffv) {
  int c = blockIdx.x, b = blockIdx.y, d = threadIdx.x;
  float acc = 0.f;
  for (int c2 = c + 1; c2 < 64; c2++) acc += ctot[(b * 64 + c2) * 256 + d];
  const float* base = vpf + (b * 4096 + c * 64) * 256 + d;
  float* sbase = suffv + (b * 4096 + c * 64) * 256 + d;
  for (int r = 63; r >= 0; r--) {
    sbase[r * 256] = acc;
    acc += base[r * 256];
  }
}

// ---------------- Split-K flash attention ----------------
// 512 blocks: bid = s*256 + c; c -> (b = c&3, j = c>>2); s==0: qt=63-j,h=1; s==1: qt=j,h=0.
// Blocks n and n+256 co-reside on a CU: paired work ~const (balanced), same batch (L2 share).
// 4 waves: wq = w&1 (32 q-rows), x = w>>1 (QK k-half / PV d-half).
// LDS: K[64][256] swz, Vt[256][64] swz, P[2][32][72], Stat[2][2][32][2]. Total 75776 B.
#define ATTN2_LDS (65536 + 32768 + 9216 + 1024)

__global__ __launch_bounds__(256, 2) void attn2_kernel(
    const unsigned short* __restrict__ qpb, const unsigned short* __restrict__ kpb,
    const unsigned short* __restrict__ vptb,
    float* __restrict__ O0, float* __restrict__ O1, float* __restrict__ mzbuf) {
  extern __shared__ char smem[];
  unsigned short(*Klds)[256] = (unsigned short(*)[256])smem;
  unsigned short(*Vlds)[64] = (unsigned short(*)[64])(smem + 65536);
  unsigned short(*Plds)[32][72] = (unsigned short(*)[32][72])(smem + 65536 + 32768);
  float(*Stat)[2][32][2] = (float(*)[2][32][2])(smem + 65536 + 32768 + 9216);  // [wq][m/s][row][x]

  int bid = blockIdx.x;
  int c = bid & 255, s = bid >> 8;
  int b = c & 3, j = c >> 2;
  int qt = s ? j : 63 - j;
  int h = s ? 0 : 1;
  int sp = (qt + 1) >> 1;
  int k0 = h ? sp : 0;
  int k1 = h ? (qt + 1) : sp;

  int tid = threadIdx.x;
  int w = tid >> 6, l = tid & 63, g = l >> 4, lm = l & 15;
  int wq = w & 1, x = w >> 1;
  int lb = lm & 7;

  // Q fragments: rows qt*64 + 32*wq + 16*rt + lm, full D. Pre-scaled by 1/16.
  bf16x8 qa[2][8];
  const unsigned short* qb0 = qpb + (b * 4096 + qt * 64 + 32 * wq) * 256;
#pragma unroll
  for (int rt = 0; rt < 2; rt++)
#pragma unroll
    for (int d0 = 0; d0 < 8; d0++)
      qa[rt][d0] = *(const bf16x8*)(qb0 + (16 * rt + lm) * 256 + d0 * 32 + 8 * g);

  float m_[2][4], Z_[2][4];
  f32x4 O[2][8];
#pragma unroll
  for (int rt = 0; rt < 2; rt++)
#pragma unroll
    for (int r = 0; r < 4; r++) { m_[rt][r] = -1e30f; Z_[rt][r] = 0.f; }
#pragma unroll
  for (int rt = 0; rt < 2; rt++)
#pragma unroll
    for (int dt = 0; dt < 8; dt++) O[rt][dt] = (f32x4){0.f, 0.f, 0.f, 0.f};

  for (int kt = k0; kt < k1; kt++) {
    // ---- stage K[64][256] and Vt[256][64], XOR-swizzled (chunk16B ^= row&7) ----
    const unsigned short* ksrc = kpb + (b * 4096 + kt * 64) * 256;
#pragma unroll
    for (int i = 0; i < 8; i++) {
      int cid = i * 256 + tid;
      int row = cid >> 5, cc = cid & 31;
      *(uint4*)&Klds[row][(cc ^ (row & 7)) * 8] = *(const uint4*)(ksrc + row * 256 + cc * 8);
    }
    const unsigned short* vsrc = vptb + (b * 256) * 4096 + kt * 64;
#pragma unroll
    for (int i = 0; i < 8; i++) {
      int cid = i * 256 + tid;
      int row = cid >> 3, cc = cid & 7;
      *(uint4*)&Vlds[row][(cc ^ (row & 7)) * 8] = *(const uint4*)(vsrc + row * 4096 + cc * 8);
    }
    __syncthreads();

    // ---- QK^T: this wave's 32 q-rows x 32 k-cols (half x) ----
    f32x4 sc_[2][2];
#pragma unroll
    for (int rt = 0; rt < 2; rt++)
#pragma unroll
      for (int jt = 0; jt < 2; jt++) sc_[rt][jt] = (f32x4){0.f, 0.f, 0.f, 0.f};
#pragma unroll
    for (int d0 = 0; d0 < 8; d0++) {
      bf16x8 kf0 = *(const bf16x8*)&Klds[x * 32 + lm][((4 * d0 + g) ^ lb) * 8];
      bf16x8 kf1 = *(const bf16x8*)&Klds[x * 32 + 16 + lm][((4 * d0 + g) ^ lb) * 8];
#pragma unroll
      for (int rt = 0; rt < 2; rt++) {
        sc_[rt][0] = __builtin_amdgcn_mfma_f32_16x16x32_bf16(qa[rt][d0], kf0, sc_[rt][0], 0, 0, 0);
        sc_[rt][1] = __builtin_amdgcn_mfma_f32_16x16x32_bf16(qa[rt][d0], kf1, sc_[rt][1], 0, 0, 0);
      }
    }

    if (kt == qt) {  // diagonal: strict upper triangle -> -inf
#pragma unroll
      for (int rt = 0; rt < 2; rt++)
#pragma unroll
        for (int jt = 0; jt < 2; jt++)
#pragma unroll
          for (int r = 0; r < 4; r++)
            if (x * 32 + jt * 16 + lm > 32 * wq + 16 * rt + 4 * g + r) sc_[rt][jt][r] = -1e30f;
    }

    // ---- local row max, cross-x merge via LDS ----
    float mx[2][4];
#pragma unroll
    for (int rt = 0; rt < 2; rt++)
#pragma unroll
      for (int r = 0; r < 4; r++) mx[rt][r] = fmaxf(sc_[rt][0][r], sc_[rt][1][r]);
#pragma unroll
    for (int off = 1; off < 16; off <<= 1)
#pragma unroll
      for (int rt = 0; rt < 2; rt++)
#pragma unroll
        for (int r = 0; r < 4; r++) mx[rt][r] = fmaxf(mx[rt][r], __shfl_xor(mx[rt][r], off, 16));
    if (lm == 0) {
#pragma unroll
      for (int rt = 0; rt < 2; rt++)
#pragma unroll
        for (int r = 0; r < 4; r++) Stat[wq][0][16 * rt + 4 * g + r][x] = mx[rt][r];
    }
    __syncthreads();

    float mn[2][4], scl[2][4], rs[2][4];
#pragma unroll
    for (int rt = 0; rt < 2; rt++)
#pragma unroll
      for (int r = 0; r < 4; r++) {
        int row = 16 * rt + 4 * g + r;
        float2 mm = *(const float2*)&Stat[wq][0][row][0];
        float mo = fmaxf(mm.x, mm.y);
        mn[rt][r] = fmaxf(m_[rt][r], mo);
        scl[rt][r] = __expf(m_[rt][r] - mn[rt][r]);
        m_[rt][r] = mn[rt][r];
        rs[rt][r] = 0.f;
      }
#pragma unroll
    for (int rt = 0; rt < 2; rt++)
#pragma unroll
      for (int jt = 0; jt < 2; jt++)
#pragma unroll
        for (int r = 0; r < 4; r++) {
          float p = __expf(sc_[rt][jt][r] - mn[rt][r]);
          rs[rt][r] += p;
          Plds[wq][16 * rt + 4 * g + r][x * 32 + jt * 16 + lm] = f2bf_u(p);
        }
#pragma unroll
    for (int off = 1; off < 16; off <<= 1)
#pragma unroll
      for (int rt = 0; rt < 2; rt++)
#pragma unroll
        for (int r = 0; r < 4; r++) rs[rt][r] += __shfl_xor(rs[rt][r], off, 16);
    if (lm == 0) {
#pragma unroll
      for (int rt = 0; rt < 2; rt++)
#pragma unroll
        for (int r = 0; r < 4; r++) Stat[wq][1][16 * rt + 4 * g + r][x] = rs[rt][r];
    }
    // rescale O while sums land
#pragma unroll
    for (int rt = 0; rt < 2; rt++)
#pragma unroll
      for (int dt = 0; dt < 8; dt++)
#pragma unroll
        for (int r = 0; r < 4; r++) O[rt][dt][r] *= scl[rt][r];
    __syncthreads();

#pragma unroll
    for (int rt = 0; rt < 2; rt++)
#pragma unroll
      for (int r = 0; r < 4; r++) {
        int row = 16 * rt + 4 * g + r;
        float2 ss = *(const float2*)&Stat[wq][1][row][0];
        Z_[rt][r] = Z_[rt][r] * scl[rt][r] + ss.x + ss.y;
      }

    // ---- PV: O[32 rows][128 cols (half x)] += P[32x64] @ V[64x128] ----
    bf16x8 pa[2][2];
#pragma unroll
    for (int rt = 0; rt < 2; rt++) {
      pa[rt][0] = *(const bf16x8*)&Plds[wq][16 * rt + lm][8 * g];
      pa[rt][1] = *(const bf16x8*)&Plds[wq][16 * rt + lm][32 + 8 * g];
    }
#pragma unroll
    for (int dt = 0; dt < 8; dt++) {
      int vrow = x * 128 + dt * 16 + lm;
      bf16x8 vf0 = *(const bf16x8*)&Vlds[vrow][(g ^ lb) * 8];
      bf16x8 vf1 = *(const bf16x8*)&Vlds[vrow][((4 + g) ^ lb) * 8];
#pragma unroll
      for (int rt = 0; rt < 2; rt++) {
        O[rt][dt] = __builtin_amdgcn_mfma_f32_16x16x32_bf16(pa[rt][0], vf0, O[rt][dt], 0, 0, 0);
        O[rt][dt] = __builtin_amdgcn_mfma_f32_16x16x32_bf16(pa[rt][1], vf1, O[rt][dt], 0, 0, 0);
      }
    }
    __syncthreads();
  }

  // ---- write partial O, m, Z ----
  float* Op = h ? O1 : O0;
#pragma unroll
  for (int rt = 0; rt < 2; rt++)
#pragma unroll
    for (int r = 0; r < 4; r++) {
      int row = 32 * wq + 16 * rt + 4 * g + r;
      int grow = b * 4096 + qt * 64 + row;
#pragma unroll
      for (int dt = 0; dt < 8; dt++)
        Op[grow * 256 + x * 128 + dt * 16 + lm] = O[rt][dt][r];
      if (x == 0 && lm == 0) {
        mzbuf[h * 16384 + grow] = m_[rt][r];
        mzbuf[32768 + h * 16384 + grow] = Z_[rt][r];
      }
    }
}

// ---------------- combine: merge halves + masked-zero correction + qp add ----------------
__global__ __launch_bounds__(256) void combine_kernel(
    const float* __restrict__ O0, const float* __restrict__ O1, const float* __restrict__ mzbuf,
    const float* __restrict__ qpf, const float* __restrict__ suffv, float* __restrict__ out) {
  int grow = blockIdx.x * 4 + (threadIdx.x >> 6);
  int col = (threadIdx.x & 63) * 4;
  float m0 = mzbuf[grow], m1 = mzbuf[16384 + grow];
  float Z0 = mzbuf[32768 + grow], Z1 = mzbuf[32768 + 16384 + grow];
  float M = fmaxf(m0, m1);
  float f0 = __expf(m0 - M), f1 = __expf(m1 - M);
  float Zm = Z0 * f0 + Z1 * f1;
  int q = grow & 4095;
  int nmask = 4095 - q;
  float scl, e0, Zf;
  if (nmask > 0) {
    float Mf = fmaxf(M, 0.f);
    scl = __expf(M - Mf);
    e0 = __expf(-Mf);
    Zf = Zm * scl + (float)nmask * e0;
  } else {
    scl = 1.f; e0 = 0.f; Zf = Zm;
  }
  float rZ = 1.f / Zf;
  float a0 = f0 * scl * rZ, a1 = f1 * scl * rZ, a2 = e0 * rZ;
  int base = grow * 256 + col;
  float4 o0 = *(const float4*)&O0[base];
  float4 o1 = *(const float4*)&O1[base];
  float4 qp = *(const float4*)&qpf[base];
  float4 sv = *(const float4*)&suffv[base];
  float4 res;
  res.x = qp.x + o0.x * a0 + o1.x * a1 + sv.x * a2;
  res.y = qp.y + o0.y * a0 + o1.y * a1 + sv.y * a2;
  res.z = qp.z + o0.z * a0 + o1.z * a1 + sv.z * a2;
  res.w = qp.w + o0.w * a0 + o1.w * a1 + sv.w * a2;
  *(float4*)&out[base] = res;
}

// ---------------- launch ----------------
extern "C" void kernel_launch(void* const* d_in, const int* in_sizes, int n_in,
                              void* d_out, int out_size, void* d_ws, size_t ws_size,
                              hipStream_t stream) {
  const float* v_in = (const float*)d_in[0];
  const float* k_in = (const float*)d_in[1];
  const float* q_in = (const float*)d_in[2];
  const float* Wq = (const float*)d_in[3];
  const float* bq = (const float*)d_in[4];
  const float* Wk = (const float*)d_in[5];
  const float* bk = (const float*)d_in[6];
  const float* Wv = (const float*)d_in[7];
  const float* bv = (const float*)d_in[8];
  float* out = (float*)d_out;

  char* p = (char*)d_ws;
  float* qpf = (float*)(p + 0);                            // 16 MB
  float* vpf = (float*)(p + 16777216);                     // 16 MB (reused as O1 by attn2)
  float* suffv = (float*)(p + 33554432);                   // 16 MB
  unsigned short* qpb = (unsigned short*)(p + 50331648);   // 8 MB (scaled 1/16)
  unsigned short* kpb = (unsigned short*)(p + 58720256);   // 8 MB
  unsigned short* vptb = (unsigned short*)(p + 67108864);  // 8 MB, [B][D][S]
  unsigned short* WTq = (unsigned short*)(p + 75497472);   // 128 KB
  unsigned short* WTk = (unsigned short*)(p + 75628544);   // 128 KB
  unsigned short* WTv = (unsigned short*)(p + 75759616);   // 128 KB
  float* mzbuf = (float*)(p + 75497472);                   // 256 KB, reuses WTq+WTk (dead after proj)
  float* ctot = (float*)(p + 75759616);                    // 256 KB, reuses WTv+old tail
  float* O1 = vpf;                                         // vpf dead after scan2
  float* O0 = out;                                         // d_out doubles as h0 partial

  hipFuncSetAttribute((const void*)attn2_kernel,
                      hipFuncAttributeMaxDynamicSharedMemorySize, ATTN2_LDS);

  wt_kernel<<<768, 256, 0, stream>>>(Wq, Wk, Wv, WTq, WTk, WTv);
  proj_kernel<<<256, 256, 0, stream>>>(q_in, WTq, bq, qpf, qpb, 0);
  proj_kernel<<<256, 256, 0, stream>>>(k_in, WTk, bk, nullptr, kpb, 1);
  proj_kernel<<<256, 256, 0, stream>>>(v_in, WTv, bv, vpf, vptb, 2);
  scan1<<<dim3(64, 4), 256, 0, stream>>>(vpf, ctot);
  scan2<<<dim3(64, 4), 256, 0, stream>>>(vpf, ctot, suffv);
  attn2_kernel<<<512, 256, ATTN2_LDS, stream>>>(qpb, kpb, vptb, O0, O1, mzbuf);
  combine_kernel<<<4096, 256, 0, stream>>>(O0, O1, mzbuf, qpf, suffv, out);
}